// Round 12
// baseline (1618.665 us; speedup 1.0000x reference)
//
#include <hip/hip_runtime.h>
#include <math.h>

#define Bn 128
#define Nn 20
#define Hn 128
#define Sn 2
#define STEPS 100
#define NTHREADS 384

__device__ __forceinline__ float wredMaxAll(float v){
  #pragma unroll
  for (int o = 32; o; o >>= 1) v = fmaxf(v, __shfl_xor(v, o));
  return v;
}
__device__ __forceinline__ float wredSumAll(float v){
  #pragma unroll
  for (int o = 32; o; o >>= 1) v += __shfl_xor(v, o);
  return v;
}
// fast transcendentals: v_exp_f32 + v_rcp_f32, branch-free, saturate correctly
__device__ __forceinline__ float frcp_(float x){ return __builtin_amdgcn_rcpf(x); }
__device__ __forceinline__ float ftanh(float x){
  float e = __expf(2.0f * x);
  return 1.0f - 2.0f * frcp_(e + 1.0f);
}
__device__ __forceinline__ float fsig(float x){ return frcp_(1.0f + __expf(-x)); }

// grid=128 on 256 CUs -> 1 WG/CU; occupancy is irrelevant. min-waves/EU=1
// frees the allocator to ~512 VGPRs so wrow[128]+wa4h[64]+scalars live in
// arch VGPRs with headroom (r7/r9/r11 spilled at the 128-VGPR cap).
__global__ __launch_bounds__(NTHREADS, 1) void cvrp_ptr_net_kernel(
    const float* __restrict__ adj,   const float* __restrict__ stat,
    const float* __restrict__ dyn,   const float* __restrict__ depot,
    const float* __restrict__ W_adj, const float* __restrict__ b_adj,
    const float* __restrict__ W_stat,const float* __restrict__ b_stat,
    const float* __restrict__ W_dyn, const float* __restrict__ b_dyn,
    const float* __restrict__ W_dec, const float* __restrict__ b_dec,
    const float* __restrict__ Wih,   const float* __restrict__ Whh,
    const float* __restrict__ bih,   const float* __restrict__ bhh,
    const float* __restrict__ attn_v,const float* __restrict__ attn_W,
    const float* __restrict__ ptr_v, const float* __restrict__ ptr_W,
    const float* __restrict__ x0,
    float* __restrict__ out_idx, float* __restrict__ out_logp)
{
  __shared__ float s_attn_pre[Hn][Nn + 1];
  __shared__ float s_ptr_pre[Hn][Nn + 1];
  __shared__ float s_p2s[Hn][Nn + 1];
  __shared__ float s_eA[Hn][Nn + 1];
  __shared__ float s_eS[Hn][Nn + 1];
  __shared__ float s_eD[Hn][Nn + 1];
  __shared__ float s_adj[Nn][Nn];
  __shared__ float s_dep[Nn];
  __shared__ float s_st[Sn][Nn];
  __shared__ float s_dy[Sn][Nn];
  __shared__ float s_wdec0[Hn], s_wdec1[Hn], s_bdec[Hn];
  __shared__ float s_av[Hn], s_pv[Hn];
  __shared__ __align__(16) float s_h[Hn];
  __shared__ float s_a[2 * Hn];
  __shared__ float s_gin[Hn], s_ghn[Hn];
  __shared__ float s_qp[2 * Hn];
  __shared__ float s_sc[Nn];
  __shared__ float s_u[Hn];
  __shared__ float s_p[Nn];
  __shared__ float s_lm[Nn];

  const int b = blockIdx.x;
  const int t = threadIdx.x;

  // ---- stage per-batch inputs & small weights ----
  for (int i = t; i < Nn * Nn; i += NTHREADS) s_adj[i / Nn][i % Nn] = adj[b * Nn * Nn + i];
  if (t < Nn) { float d = depot[b * Nn + t]; s_dep[t] = d; s_lm[t] = logf(d); }
  for (int i = t; i < Sn * Nn; i += NTHREADS) {
    s_st[i / Nn][i % Nn] = stat[b * Sn * Nn + i];
    s_dy[i / Nn][i % Nn] = dyn[b * Sn * Nn + i];
  }
  if (t < Hn) {
    s_wdec0[t] = W_dec[t * Sn]; s_wdec1[t] = W_dec[t * Sn + 1]; s_bdec[t] = b_dec[t];
    s_av[t] = attn_v[t]; s_pv[t] = ptr_v[t];
    s_h[t] = 0.0f;
  }
  __syncthreads();

  // ---- node embeddings ----
  for (int idx = t; idx < Hn * Nn; idx += NTHREADS) {
    int h = idx / Nn, n = idx - h * Nn;
    const float* wa = W_adj + h * (Nn + 1);
    float accA = b_adj[h];
    #pragma unroll
    for (int c = 0; c < Nn; ++c) accA += wa[c] * s_adj[c][n];
    accA += wa[Nn] * s_dep[n];
    s_eA[h][n] = accA;
    s_eS[h][n] = b_stat[h] + W_stat[h * Sn] * s_st[0][n] + W_stat[h * Sn + 1] * s_st[1][n];
    s_eD[h][n] = b_dyn[h]  + W_dyn[h * Sn]  * s_dy[0][n] + W_dyn[h * Sn + 1]  * s_dy[1][n];
  }
  __syncthreads();

  // ---- loop-invariant tables ----
  for (int idx = t; idx < Hn * Nn; idx += NTHREADS) {
    int h = idx / Nn, n = idx - h * Nn;
    const float* aw = attn_W + h * (4 * Hn);
    const float* pw = ptr_W + h * (2 * Hn);
    float acc = 0.f, p1 = 0.f, p2 = 0.f;
    for (int k = 0; k < Hn; ++k) {
      float es = s_eS[k][n];
      acc += aw[k] * s_eA[k][n] + aw[Hn + k] * es + aw[2 * Hn + k] * s_eD[k][n];
      p1  += pw[k] * es;
      p2  += pw[Hn + k] * es;
    }
    s_attn_pre[h][n] = acc; s_ptr_pre[h][n] = p1; s_p2s[h][n] = p2;
  }

  // ---- folded GRU-input coefficients ----
  float g0 = 0.f, g1 = 0.f, gc = 0.f;
  {
    const float* wi = Wih + t * Hn;
    for (int h2 = 0; h2 < Hn; ++h2) {
      float w = wi[h2];
      g0 += w * s_wdec0[h2]; g1 += w * s_wdec1[h2]; gc += w * s_bdec[h2];
    }
    gc += bih[t];
  }
  const float bhh_t = bhh[t];

  // ---- weight registers ----
  float wrow[Hn];
  {
    const float4* src = (const float4*)(Whh + t * Hn);
    #pragma unroll
    for (int c = 0; c < Hn / 4; ++c) {
      float4 v = src[c];
      wrow[4 * c] = v.x; wrow[4 * c + 1] = v.y; wrow[4 * c + 2] = v.z; wrow[4 * c + 3] = v.w;
    }
  }
  float wa4h[64];
  {
    int r = t & (Hn - 1), half = (t >> 7) & 1;
    const float4* src = (const float4*)(attn_W + r * 4 * Hn + 3 * Hn + half * 64);
    #pragma unroll
    for (int c = 0; c < 16; ++c) {
      float4 v = src[c];
      wa4h[4 * c] = v.x; wa4h[4 * c + 1] = v.y; wa4h[4 * c + 2] = v.z; wa4h[4 * c + 3] = v.w;
    }
  }
  __syncthreads();

  float dec0 = x0[0], dec1 = x0[1];
  float gh_reg = bhh_t;                 // gh for h0=0 is just bhh
  float* oi = out_idx + b * STEPS;
  float* ol = out_logp + b * STEPS;

  for (int step = 0; step < STEPS; ++step) {
    // P1' (tiny): gi = folded(dec) ; publish gi+gh_reg (gh from prev P3')
    {
      float gi = g0 * dec0 + g1 * dec1 + gc;
      if (t < 2 * Hn) s_a[t] = gi + gh_reg;
      else { s_gin[t - 2 * Hn] = gi; s_ghn[t - 2 * Hn] = gh_reg; }
    }
    __syncthreads();                                    // b1

    // P2: GRU elementwise -> h_new in place
    if (t < Hn) {
      float rr = fsig(s_a[t]);
      float zz = fsig(s_a[Hn + t]);
      float nn = ftanh(s_gin[t] + rr * s_ghn[t]);
      s_h[t] = (1.0f - zz) * nn + zz * s_h[t];
    }
    __syncthreads();                                    // b2

    // P3': gh_next = Whh@h_new (all threads, into gh_reg) ; q halves (t<256)
    {
      float a0 = 0.f, a1 = 0.f, a2 = 0.f, a3 = 0.f;
      const float4* h4 = (const float4*)s_h;
      #pragma unroll
      for (int c = 0; c < Hn / 4; ++c) {
        float4 hv = h4[c];
        a0 += wrow[4 * c] * hv.x; a1 += wrow[4 * c + 1] * hv.y;
        a2 += wrow[4 * c + 2] * hv.z; a3 += wrow[4 * c + 3] * hv.w;
      }
      gh_reg = bhh_t + (a0 + a1) + (a2 + a3);
      if (t < 2 * Hn) {
        int half = t >> 7;
        float q0 = 0.f, q1 = 0.f, q2 = 0.f, q3 = 0.f;
        const float4* hh = (const float4*)(s_h + half * 64);
        #pragma unroll
        for (int c = 0; c < 16; ++c) {
          float4 hv = hh[c];
          q0 += wa4h[4 * c] * hv.x; q1 += wa4h[4 * c + 1] * hv.y;
          q2 += wa4h[4 * c + 2] * hv.z; q3 += wa4h[4 * c + 3] * hv.w;
        }
        s_qp[t] = (q0 + q1) + (q2 + q3);
      }
    }
    __syncthreads();                                    // b3

    // P4: attention scores (swizzled bank order)
    if (t < 320) {
      int n = t >> 4, g = t & 15;
      float part = 0.f;
      #pragma unroll
      for (int i = 0; i < 8; ++i) {
        int h2 = g * 8 + ((i + g) & 7);
        float qv = s_qp[h2] + s_qp[h2 + 128];
        part += s_av[h2] * ftanh(s_attn_pre[h2][n] + qv);
      }
      part += __shfl_xor(part, 8);
      part += __shfl_xor(part, 4);
      part += __shfl_xor(part, 2);
      part += __shfl_xor(part, 1);
      if (g == 0) s_sc[n] = part;
    }
    __syncthreads();                                    // b4

    // P5+P6 fused (t<128): redundant in-wave softmax + u = P2S @ attn
    if (t < Hn) {
      int lane = t & 63;
      float v = (lane < Nn) ? s_sc[lane] : -INFINITY;
      float m = wredMaxAll(v);
      float e = (lane < Nn) ? __expf(v - m) : 0.f;
      float ssum = wredSumAll(e);
      float inv = frcp_(ssum);
      float acc = 0.f;
      #pragma unroll
      for (int n = 0; n < Nn; ++n) {
        float an = __shfl(e, n);
        acc += s_p2s[t][n] * an;
      }
      s_u[t] = acc * inv;
    }
    __syncthreads();                                    // b5

    // P7: pointer scores (swizzled)
    if (t < 320) {
      int n = t >> 4, g = t & 15;
      float part = 0.f;
      #pragma unroll
      for (int i = 0; i < 8; ++i) {
        int h2 = g * 8 + ((i + g) & 7);
        part += s_pv[h2] * ftanh(s_ptr_pre[h2][n] + s_u[h2]);
      }
      part += __shfl_xor(part, 8);
      part += __shfl_xor(part, 4);
      part += __shfl_xor(part, 2);
      part += __shfl_xor(part, 1);
      if (g == 0) s_p[n] = part;
    }
    __syncthreads();                                    // b6

    // P8: all-wave redundant argmax (ballot is wave-uniform); dec in regs;
    //     no trailing barrier (s_p rewrite sits behind b1..b6 of step k+1)
    {
      int lane = t & 63;
      float v = (lane < Nn) ? (s_p[lane] + s_lm[lane]) : -INFINITY;
      float m = wredMaxAll(v);
      unsigned long long mask = __ballot(v == m);
      int amax = __ffsll(mask) - 1;
      dec0 = s_st[0][amax];
      dec1 = s_st[1][amax];
      if (t < 64) {
        float e = (lane < Nn) ? __expf(v - m) : 0.f;
        float ssum = wredSumAll(e);
        if (t == 0) {
          oi[step] = (float)amax;
          ol[step] = -__logf(ssum);
        }
      }
    }
  }
}

extern "C" void kernel_launch(void* const* d_in, const int* in_sizes, int n_in,
                              void* d_out, int out_size, void* d_ws, size_t ws_size,
                              hipStream_t stream) {
  (void)in_sizes; (void)n_in; (void)d_ws; (void)ws_size; (void)out_size;
  const float* adj    = (const float*)d_in[0];
  const float* stat   = (const float*)d_in[1];
  const float* dynp   = (const float*)d_in[2];
  const float* depot  = (const float*)d_in[3];
  const float* W_adj  = (const float*)d_in[4];
  const float* b_adj  = (const float*)d_in[5];
  const float* W_stat = (const float*)d_in[6];
  const float* b_stat = (const float*)d_in[7];
  const float* W_dyn  = (const float*)d_in[8];
  const float* b_dyn  = (const float*)d_in[9];
  const float* W_dec  = (const float*)d_in[10];
  const float* b_dec  = (const float*)d_in[11];
  const float* Wih    = (const float*)d_in[12];
  const float* Whh    = (const float*)d_in[13];
  const float* bih    = (const float*)d_in[14];
  const float* bhh    = (const float*)d_in[15];
  const float* attn_v = (const float*)d_in[16];
  const float* attn_W = (const float*)d_in[17];
  const float* ptr_v  = (const float*)d_in[18];
  const float* ptr_W  = (const float*)d_in[19];
  const float* x0     = (const float*)d_in[20];

  float* out = (float*)d_out;
  hipMemcpyAsync(out, dynp, (size_t)Bn * Sn * Nn * sizeof(float),
                 hipMemcpyDeviceToDevice, stream);
  float* out_idx  = out + Bn * Sn * Nn;
  float* out_logp = out + Bn * Sn * Nn + Bn * STEPS;

  cvrp_ptr_net_kernel<<<Bn, NTHREADS, 0, stream>>>(
      adj, stat, dynp, depot, W_adj, b_adj, W_stat, b_stat, W_dyn, b_dyn,
      W_dec, b_dec, Wih, Whh, bih, bhh, attn_v, attn_W, ptr_v, ptr_W, x0,
      out_idx, out_logp);
}

// Round 14
// 544.059 us; speedup vs baseline: 2.9752x; 2.9752x over previous
//
#include <hip/hip_runtime.h>
#include <math.h>

#define Bn 128
#define Nn 20
#define Hn 128
#define Sn 2
#define STEPS 100
#define NTHREADS 768

__device__ __forceinline__ float wredMaxAll(float v){
  #pragma unroll
  for (int o = 32; o; o >>= 1) v = fmaxf(v, __shfl_xor(v, o));
  return v;
}
__device__ __forceinline__ float wredSumAll(float v){
  #pragma unroll
  for (int o = 32; o; o >>= 1) v += __shfl_xor(v, o);
  return v;
}
__device__ __forceinline__ float frcp_(float x){ return __builtin_amdgcn_rcpf(x); }
__device__ __forceinline__ float ftanh(float x){
  float e = __expf(2.0f * x);
  return 1.0f - 2.0f * frcp_(e + 1.0f);
}
__device__ __forceinline__ float fsig(float x){ return frcp_(1.0f + __expf(-x)); }

// 768 threads: weight arrays split across lanes (Whh half-rows 64f, Wa4
// quarter-rows 32f) so per-thread register demand ~121 fits the 128-VGPR
// pin observed in r5-r12 (192f arrays + extra scalars = spill storm, r12).
__global__ __launch_bounds__(NTHREADS) void cvrp_ptr_net_kernel(
    const float* __restrict__ adj,   const float* __restrict__ stat,
    const float* __restrict__ dyn,   const float* __restrict__ depot,
    const float* __restrict__ W_adj, const float* __restrict__ b_adj,
    const float* __restrict__ W_stat,const float* __restrict__ b_stat,
    const float* __restrict__ W_dyn, const float* __restrict__ b_dyn,
    const float* __restrict__ W_dec, const float* __restrict__ b_dec,
    const float* __restrict__ Wih,   const float* __restrict__ Whh,
    const float* __restrict__ bih,   const float* __restrict__ bhh,
    const float* __restrict__ attn_v,const float* __restrict__ attn_W,
    const float* __restrict__ ptr_v, const float* __restrict__ ptr_W,
    const float* __restrict__ x0,
    float* __restrict__ out_idx, float* __restrict__ out_logp)
{
  __shared__ float s_attn_pre[Hn][Nn + 1];
  __shared__ float s_ptr_pre[Hn][Nn + 1];
  __shared__ float s_p2s[Hn][Nn + 1];
  __shared__ float s_eA[Hn][Nn + 1];
  __shared__ float s_eS[Hn][Nn + 1];
  __shared__ float s_eD[Hn][Nn + 1];
  __shared__ float s_adj[Nn][Nn];
  __shared__ float s_dep[Nn];
  __shared__ float s_st[Sn][Nn];
  __shared__ float s_dy[Sn][Nn];
  __shared__ float s_wdec0[Hn], s_wdec1[Hn], s_bdec[Hn];
  __shared__ float s_av[Hn], s_pv[Hn];
  __shared__ __align__(16) float s_h[Hn];
  __shared__ float s_a[2 * Hn];
  __shared__ float s_gin[Hn], s_ghn[Hn];
  __shared__ float s_q[Hn];
  __shared__ float s_sc[Nn];
  __shared__ float s_u[Hn];
  __shared__ float s_p[Nn];
  __shared__ float s_lm[Nn];

  const int b = blockIdx.x;
  const int t = threadIdx.x;
  const int wv = t >> 6;           // wave 0..11
  const int ln = t & 63;           // lane

  // gh pair-split: row = wv*32 + (ln&31), half = ln>>5
  const int rrow  = wv * 32 + (ln & 31);
  const int rhalf = ln >> 5;
  // q quad-split (t<512): qrow = wv*16 + (ln&15), quarter = ln>>4
  const int qrow   = wv * 16 + (ln & 15);
  const int qquart = ln >> 4;

  // ---- stage per-batch inputs & small weights ----
  for (int i = t; i < Nn * Nn; i += NTHREADS) s_adj[i / Nn][i % Nn] = adj[b * Nn * Nn + i];
  if (t < Nn) { float d = depot[b * Nn + t]; s_dep[t] = d; s_lm[t] = logf(d); }
  for (int i = t; i < Sn * Nn; i += NTHREADS) {
    s_st[i / Nn][i % Nn] = stat[b * Sn * Nn + i];
    s_dy[i / Nn][i % Nn] = dyn[b * Sn * Nn + i];
  }
  if (t < Hn) {
    s_wdec0[t] = W_dec[t * Sn]; s_wdec1[t] = W_dec[t * Sn + 1]; s_bdec[t] = b_dec[t];
    s_av[t] = attn_v[t]; s_pv[t] = ptr_v[t];
    s_h[t] = 0.0f;
  }
  __syncthreads();

  // ---- node embeddings ----
  for (int idx = t; idx < Hn * Nn; idx += NTHREADS) {
    int h = idx / Nn, n = idx - h * Nn;
    const float* wa = W_adj + h * (Nn + 1);
    float accA = b_adj[h];
    #pragma unroll
    for (int c = 0; c < Nn; ++c) accA += wa[c] * s_adj[c][n];
    accA += wa[Nn] * s_dep[n];
    s_eA[h][n] = accA;
    s_eS[h][n] = b_stat[h] + W_stat[h * Sn] * s_st[0][n] + W_stat[h * Sn + 1] * s_st[1][n];
    s_eD[h][n] = b_dyn[h]  + W_dyn[h * Sn]  * s_dy[0][n] + W_dyn[h * Sn + 1]  * s_dy[1][n];
  }
  __syncthreads();

  // ---- loop-invariant tables ----
  for (int idx = t; idx < Hn * Nn; idx += NTHREADS) {
    int h = idx / Nn, n = idx - h * Nn;
    const float* aw = attn_W + h * (4 * Hn);
    const float* pw = ptr_W + h * (2 * Hn);
    float acc = 0.f, p1 = 0.f, p2 = 0.f;
    for (int k = 0; k < Hn; ++k) {
      float es = s_eS[k][n];
      acc += aw[k] * s_eA[k][n] + aw[Hn + k] * es + aw[2 * Hn + k] * s_eD[k][n];
      p1  += pw[k] * es;
      p2  += pw[Hn + k] * es;
    }
    s_attn_pre[h][n] = acc; s_ptr_pre[h][n] = p1; s_p2s[h][n] = p2;
  }

  // ---- folded GRU-input coefficients for my row ----
  float g0 = 0.f, g1 = 0.f, gc = 0.f;
  {
    const float* wi = Wih + rrow * Hn;
    for (int j = 0; j < Hn; ++j) {
      float w = wi[j];
      g0 += w * s_wdec0[j]; g1 += w * s_wdec1[j]; gc += w * s_bdec[j];
    }
    gc += bih[rrow];
  }
  const float bhh_r = bhh[rrow];

  // ---- weight registers: Whh half-row (64) + Wa4 quarter-row (32) ----
  float wrowh[64];
  {
    const float4* src = (const float4*)(Whh + rrow * Hn + rhalf * 64);
    #pragma unroll
    for (int c = 0; c < 16; ++c) {
      float4 v = src[c];
      wrowh[4 * c] = v.x; wrowh[4 * c + 1] = v.y; wrowh[4 * c + 2] = v.z; wrowh[4 * c + 3] = v.w;
    }
  }
  float wa4q[32];
  if (t < 512) {
    const float4* src = (const float4*)(attn_W + qrow * 4 * Hn + 3 * Hn + qquart * 32);
    #pragma unroll
    for (int c = 0; c < 8; ++c) {
      float4 v = src[c];
      wa4q[4 * c] = v.x; wa4q[4 * c + 1] = v.y; wa4q[4 * c + 2] = v.z; wa4q[4 * c + 3] = v.w;
    }
  }
  __syncthreads();

  float dec0 = x0[0], dec1 = x0[1];
  float gh_reg = bhh_r;                 // gh(h0=0) = bhh
  float* oi = out_idx + b * STEPS;
  float* ol = out_logp + b * STEPS;

  for (int step = 0; step < STEPS; ++step) {
    // P1' (tiny): gi fold + publish gi/gh (lane<32 of each wave owns row rrow)
    if ((ln >> 5) == 0) {
      float gi = g0 * dec0 + g1 * dec1 + gc;
      if (rrow < 2 * Hn) s_a[rrow] = gi + gh_reg;
      else { s_gin[rrow - 2 * Hn] = gi; s_ghn[rrow - 2 * Hn] = gh_reg; }
    }
    __syncthreads();                                    // b1

    // P2: GRU elementwise -> h_new
    if (t < Hn) {
      float rr = fsig(s_a[t]);
      float zz = fsig(s_a[Hn + t]);
      float nn = ftanh(s_gin[t] + rr * s_ghn[t]);
      s_h[t] = (1.0f - zz) * nn + zz * s_h[t];
    }
    __syncthreads();                                    // b2

    // P3': q = Wa4@h (quad-split, t<512) ; gh_next = Whh@h (pair-split, all)
    {
      if (t < 512) {
        float qp = 0.f;
        const float4* hh = (const float4*)(s_h + qquart * 32);
        #pragma unroll
        for (int c = 0; c < 8; ++c) {
          float4 hv = hh[c];
          qp += wa4q[4 * c] * hv.x + wa4q[4 * c + 1] * hv.y
              + wa4q[4 * c + 2] * hv.z + wa4q[4 * c + 3] * hv.w;
        }
        qp += __shfl_xor(qp, 16);
        qp += __shfl_xor(qp, 32);
        if (ln < 16) s_q[qrow] = qp;
      }
      float a0 = 0.f, a1 = 0.f, a2 = 0.f, a3 = 0.f;
      const float4* h4 = (const float4*)(s_h + rhalf * 64);
      #pragma unroll
      for (int c = 0; c < 16; ++c) {
        float4 hv = h4[c];
        a0 += wrowh[4 * c] * hv.x; a1 += wrowh[4 * c + 1] * hv.y;
        a2 += wrowh[4 * c + 2] * hv.z; a3 += wrowh[4 * c + 3] * hv.w;
      }
      float part = (a0 + a1) + (a2 + a3);
      part += __shfl_xor(part, 32);
      gh_reg = bhh_r + part;
    }
    __syncthreads();                                    // b3

    // P4: attention scores — 640 threads, 4 ftanh each, 32-lane group reduce
    if (t < 32 * Nn) {
      int n = t >> 5, g = t & 31;
      float part = 0.f;
      #pragma unroll
      for (int i = 0; i < 4; ++i) {
        int h2 = g * 4 + ((i + g) & 3);
        part += s_av[h2] * ftanh(s_attn_pre[h2][n] + s_q[h2]);
      }
      part += __shfl_xor(part, 16);
      part += __shfl_xor(part, 8);
      part += __shfl_xor(part, 4);
      part += __shfl_xor(part, 2);
      part += __shfl_xor(part, 1);
      if (g == 0) s_sc[n] = part;
    }
    __syncthreads();                                    // b4

    // P5+P6 fused (t<128): redundant in-wave softmax + u = P2S @ attn
    if (t < Hn) {
      int lane = t & 63;
      float v = (lane < Nn) ? s_sc[lane] : -INFINITY;
      float m = wredMaxAll(v);
      float e = (lane < Nn) ? __expf(v - m) : 0.f;
      float ssum = wredSumAll(e);
      float inv = frcp_(ssum);
      float acc = 0.f;
      #pragma unroll
      for (int n = 0; n < Nn; ++n) {
        float an = __shfl(e, n);
        acc += s_p2s[t][n] * an;
      }
      s_u[t] = acc * inv;
    }
    __syncthreads();                                    // b5

    // P7: pointer scores — 640 threads, 4 ftanh each
    if (t < 32 * Nn) {
      int n = t >> 5, g = t & 31;
      float part = 0.f;
      #pragma unroll
      for (int i = 0; i < 4; ++i) {
        int h2 = g * 4 + ((i + g) & 3);
        part += s_pv[h2] * ftanh(s_ptr_pre[h2][n] + s_u[h2]);
      }
      part += __shfl_xor(part, 16);
      part += __shfl_xor(part, 8);
      part += __shfl_xor(part, 4);
      part += __shfl_xor(part, 2);
      part += __shfl_xor(part, 1);
      if (g == 0) s_p[n] = part;
    }
    __syncthreads();                                    // b6

    // P8: all-wave redundant argmax (ballot wave-uniform); dec in regs;
    //     no trailing barrier (next s_p write is fenced by b1..b5(k+1))
    {
      float v = (ln < Nn) ? (s_p[ln] + s_lm[ln]) : -INFINITY;
      float m = wredMaxAll(v);
      unsigned long long mask = __ballot(v == m);
      int amax = __ffsll(mask) - 1;
      dec0 = s_st[0][amax];
      dec1 = s_st[1][amax];
      if (t < 64) {
        float e = (ln < Nn) ? __expf(v - m) : 0.f;
        float ssum = wredSumAll(e);
        if (t == 0) {
          oi[step] = (float)amax;
          ol[step] = -__logf(ssum);
        }
      }
    }
  }
}

extern "C" void kernel_launch(void* const* d_in, const int* in_sizes, int n_in,
                              void* d_out, int out_size, void* d_ws, size_t ws_size,
                              hipStream_t stream) {
  (void)in_sizes; (void)n_in; (void)d_ws; (void)ws_size; (void)out_size;
  const float* adj    = (const float*)d_in[0];
  const float* stat   = (const float*)d_in[1];
  const float* dynp   = (const float*)d_in[2];
  const float* depot  = (const float*)d_in[3];
  const float* W_adj  = (const float*)d_in[4];
  const float* b_adj  = (const float*)d_in[5];
  const float* W_stat = (const float*)d_in[6];
  const float* b_stat = (const float*)d_in[7];
  const float* W_dyn  = (const float*)d_in[8];
  const float* b_dyn  = (const float*)d_in[9];
  const float* W_dec  = (const float*)d_in[10];
  const float* b_dec  = (const float*)d_in[11];
  const float* Wih    = (const float*)d_in[12];
  const float* Whh    = (const float*)d_in[13];
  const float* bih    = (const float*)d_in[14];
  const float* bhh    = (const float*)d_in[15];
  const float* attn_v = (const float*)d_in[16];
  const float* attn_W = (const float*)d_in[17];
  const float* ptr_v  = (const float*)d_in[18];
  const float* ptr_W  = (const float*)d_in[19];
  const float* x0     = (const float*)d_in[20];

  float* out = (float*)d_out;
  hipMemcpyAsync(out, dynp, (size_t)Bn * Sn * Nn * sizeof(float),
                 hipMemcpyDeviceToDevice, stream);
  float* out_idx  = out + Bn * Sn * Nn;
  float* out_logp = out + Bn * Sn * Nn + Bn * STEPS;

  cvrp_ptr_net_kernel<<<Bn, NTHREADS, 0, stream>>>(
      adj, stat, dynp, depot, W_adj, b_adj, W_stat, b_stat, W_dyn, b_dyn,
      W_dec, b_dec, Wih, Whh, bih, bhh, attn_v, attn_W, ptr_v, ptr_W, x0,
      out_idx, out_logp);
}

// Round 15
// 465.851 us; speedup vs baseline: 3.4746x; 1.1679x over previous
//
#include <hip/hip_runtime.h>
#include <math.h>

#define Bn 128
#define Nn 20
#define Hn 128
#define Sn 2
#define STEPS 100
#define NTHREADS 768

__device__ __forceinline__ float wredMaxAll(float v){
  #pragma unroll
  for (int o = 32; o; o >>= 1) v = fmaxf(v, __shfl_xor(v, o));
  return v;
}
__device__ __forceinline__ float wredSumAll(float v){
  #pragma unroll
  for (int o = 32; o; o >>= 1) v += __shfl_xor(v, o);
  return v;
}
__device__ __forceinline__ float frcp_(float x){ return __builtin_amdgcn_rcpf(x); }
__device__ __forceinline__ float ftanh(float x){
  float e = __expf(2.0f * x);
  return 1.0f - 2.0f * frcp_(e + 1.0f);
}
__device__ __forceinline__ float fsig(float x){ return frcp_(1.0f + __expf(-x)); }

// 768 threads, 5 barriers/step. Whh half-rows (64f) + Wa4 quarter-rows (32f)
// in registers (r14-proven, 84 VGPR). gh published to s_gh in P3' (one step
// ahead); gi computed locally in P2 from 9 folded coeffs -> P1'/b1 removed.
__global__ __launch_bounds__(NTHREADS) void cvrp_ptr_net_kernel(
    const float* __restrict__ adj,   const float* __restrict__ stat,
    const float* __restrict__ dyn,   const float* __restrict__ depot,
    const float* __restrict__ W_adj, const float* __restrict__ b_adj,
    const float* __restrict__ W_stat,const float* __restrict__ b_stat,
    const float* __restrict__ W_dyn, const float* __restrict__ b_dyn,
    const float* __restrict__ W_dec, const float* __restrict__ b_dec,
    const float* __restrict__ Wih,   const float* __restrict__ Whh,
    const float* __restrict__ bih,   const float* __restrict__ bhh,
    const float* __restrict__ attn_v,const float* __restrict__ attn_W,
    const float* __restrict__ ptr_v, const float* __restrict__ ptr_W,
    const float* __restrict__ x0,
    float* __restrict__ out_idx, float* __restrict__ out_logp)
{
  __shared__ float s_attn_pre[Hn][Nn + 1];
  __shared__ float s_ptr_pre[Hn][Nn + 1];
  __shared__ float s_p2s[Hn][Nn + 1];
  __shared__ float s_eA[Hn][Nn + 1];
  __shared__ float s_eS[Hn][Nn + 1];
  __shared__ float s_eD[Hn][Nn + 1];
  __shared__ float s_adj[Nn][Nn];
  __shared__ float s_dep[Nn];
  __shared__ float s_st[Sn][Nn];
  __shared__ float s_dy[Sn][Nn];
  __shared__ float s_wdec0[Hn], s_wdec1[Hn], s_bdec[Hn];
  __shared__ float s_av[Hn], s_pv[Hn];
  __shared__ __align__(16) float s_h[Hn];
  __shared__ float s_gh[3 * Hn];       // Whh@h + bhh, written one step ahead
  __shared__ float s_q[Hn];
  __shared__ float s_sc[Nn];
  __shared__ float s_u[Hn];
  __shared__ float s_p[Nn];
  __shared__ float s_lm[Nn];

  const int b = blockIdx.x;
  const int t = threadIdx.x;
  const int wv = t >> 6;           // wave 0..11
  const int ln = t & 63;           // lane

  // gh pair-split: row = wv*32 + (ln&31), half = ln>>5
  const int rrow  = wv * 32 + (ln & 31);
  const int rhalf = ln >> 5;
  // q quad-split (t<512): qrow = wv*16 + (ln&15), quarter = ln>>4
  const int qrow   = wv * 16 + (ln & 15);
  const int qquart = ln >> 4;

  // ---- stage per-batch inputs & small weights ----
  for (int i = t; i < Nn * Nn; i += NTHREADS) s_adj[i / Nn][i % Nn] = adj[b * Nn * Nn + i];
  if (t < Nn) { float d = depot[b * Nn + t]; s_dep[t] = d; s_lm[t] = logf(d); }
  for (int i = t; i < Sn * Nn; i += NTHREADS) {
    s_st[i / Nn][i % Nn] = stat[b * Sn * Nn + i];
    s_dy[i / Nn][i % Nn] = dyn[b * Sn * Nn + i];
  }
  if (t < Hn) {
    s_wdec0[t] = W_dec[t * Sn]; s_wdec1[t] = W_dec[t * Sn + 1]; s_bdec[t] = b_dec[t];
    s_av[t] = attn_v[t]; s_pv[t] = ptr_v[t];
    s_h[t] = 0.0f;
  }
  if (t < 3 * Hn) s_gh[t] = bhh[t];   // gh(h0=0) = bhh
  __syncthreads();

  // ---- node embeddings ----
  for (int idx = t; idx < Hn * Nn; idx += NTHREADS) {
    int h = idx / Nn, n = idx - h * Nn;
    const float* wa = W_adj + h * (Nn + 1);
    float accA = b_adj[h];
    #pragma unroll
    for (int c = 0; c < Nn; ++c) accA += wa[c] * s_adj[c][n];
    accA += wa[Nn] * s_dep[n];
    s_eA[h][n] = accA;
    s_eS[h][n] = b_stat[h] + W_stat[h * Sn] * s_st[0][n] + W_stat[h * Sn + 1] * s_st[1][n];
    s_eD[h][n] = b_dyn[h]  + W_dyn[h * Sn]  * s_dy[0][n] + W_dyn[h * Sn + 1]  * s_dy[1][n];
  }
  __syncthreads();

  // ---- loop-invariant tables ----
  for (int idx = t; idx < Hn * Nn; idx += NTHREADS) {
    int h = idx / Nn, n = idx - h * Nn;
    const float* aw = attn_W + h * (4 * Hn);
    const float* pw = ptr_W + h * (2 * Hn);
    float acc = 0.f, p1 = 0.f, p2 = 0.f;
    for (int k = 0; k < Hn; ++k) {
      float es = s_eS[k][n];
      acc += aw[k] * s_eA[k][n] + aw[Hn + k] * es + aw[2 * Hn + k] * s_eD[k][n];
      p1  += pw[k] * es;
      p2  += pw[Hn + k] * es;
    }
    s_attn_pre[h][n] = acc; s_ptr_pre[h][n] = p1; s_p2s[h][n] = p2;
  }

  // ---- gi fold: t<128 holds 9 coeffs for its 3 gate-rows (named scalars) ----
  float c_r0 = 0.f, c_r1 = 0.f, c_rc = 0.f;
  float c_z0 = 0.f, c_z1 = 0.f, c_zc = 0.f;
  float c_n0 = 0.f, c_n1 = 0.f, c_nc = 0.f;
  if (t < Hn) {
    const float* wr_ = Wih + t * Hn;
    const float* wz_ = Wih + (Hn + t) * Hn;
    const float* wn_ = Wih + (2 * Hn + t) * Hn;
    for (int j = 0; j < Hn; ++j) {
      float d0 = s_wdec0[j], d1 = s_wdec1[j], db = s_bdec[j];
      float wr = wr_[j], wz = wz_[j], wn = wn_[j];
      c_r0 += wr * d0; c_r1 += wr * d1; c_rc += wr * db;
      c_z0 += wz * d0; c_z1 += wz * d1; c_zc += wz * db;
      c_n0 += wn * d0; c_n1 += wn * d1; c_nc += wn * db;
    }
    c_rc += bih[t]; c_zc += bih[Hn + t]; c_nc += bih[2 * Hn + t];
  }
  const float bhh_r = bhh[rrow];

  // ---- weight registers: Whh half-row (64) + Wa4 quarter-row (32) ----
  float wrowh[64];
  {
    const float4* src = (const float4*)(Whh + rrow * Hn + rhalf * 64);
    #pragma unroll
    for (int c = 0; c < 16; ++c) {
      float4 v = src[c];
      wrowh[4 * c] = v.x; wrowh[4 * c + 1] = v.y; wrowh[4 * c + 2] = v.z; wrowh[4 * c + 3] = v.w;
    }
  }
  float wa4q[32];
  if (t < 512) {
    const float4* src = (const float4*)(attn_W + qrow * 4 * Hn + 3 * Hn + qquart * 32);
    #pragma unroll
    for (int c = 0; c < 8; ++c) {
      float4 v = src[c];
      wa4q[4 * c] = v.x; wa4q[4 * c + 1] = v.y; wa4q[4 * c + 2] = v.z; wa4q[4 * c + 3] = v.w;
    }
  }
  __syncthreads();

  float dec0 = x0[0], dec1 = x0[1];
  float* oi = out_idx + b * STEPS;
  float* ol = out_logp + b * STEPS;

  for (int step = 0; step < STEPS; ++step) {
    // P2: GRU with local gi (t<128): reads s_gh (written by P3' of prev step)
    if (t < Hn) {
      float gh_r = s_gh[t], gh_z = s_gh[Hn + t], gh_n = s_gh[2 * Hn + t];
      float gi_r = c_r0 * dec0 + c_r1 * dec1 + c_rc;
      float gi_z = c_z0 * dec0 + c_z1 * dec1 + c_zc;
      float gi_n = c_n0 * dec0 + c_n1 * dec1 + c_nc;
      float rr = fsig(gi_r + gh_r);
      float zz = fsig(gi_z + gh_z);
      float nn = ftanh(gi_n + rr * gh_n);
      s_h[t] = (1.0f - zz) * nn + zz * s_h[t];
    }
    __syncthreads();                                    // b2

    // P3': q = Wa4@h (quad-split, t<512) ; gh_next = Whh@h + bhh -> s_gh
    {
      if (t < 512) {
        float qp = 0.f;
        const float4* hh = (const float4*)(s_h + qquart * 32);
        #pragma unroll
        for (int c = 0; c < 8; ++c) {
          float4 hv = hh[c];
          qp += wa4q[4 * c] * hv.x + wa4q[4 * c + 1] * hv.y
              + wa4q[4 * c + 2] * hv.z + wa4q[4 * c + 3] * hv.w;
        }
        qp += __shfl_xor(qp, 16);
        qp += __shfl_xor(qp, 32);
        if (ln < 16) s_q[qrow] = qp;
      }
      float a0 = 0.f, a1 = 0.f, a2 = 0.f, a3 = 0.f;
      const float4* h4 = (const float4*)(s_h + rhalf * 64);
      #pragma unroll
      for (int c = 0; c < 16; ++c) {
        float4 hv = h4[c];
        a0 += wrowh[4 * c] * hv.x; a1 += wrowh[4 * c + 1] * hv.y;
        a2 += wrowh[4 * c + 2] * hv.z; a3 += wrowh[4 * c + 3] * hv.w;
      }
      float part = (a0 + a1) + (a2 + a3);
      part += __shfl_xor(part, 32);
      if ((ln >> 5) == 0) s_gh[rrow] = bhh_r + part;
    }
    __syncthreads();                                    // b3

    // P4: attention scores — h2 = i*32+g: stride-1 across lanes, 32 banks, conflict-free
    if (t < 32 * Nn) {
      int n = t >> 5, g = t & 31;
      float part = 0.f;
      #pragma unroll
      for (int i = 0; i < 4; ++i) {
        int h2 = i * 32 + g;
        part += s_av[h2] * ftanh(s_attn_pre[h2][n] + s_q[h2]);
      }
      part += __shfl_xor(part, 16);
      part += __shfl_xor(part, 8);
      part += __shfl_xor(part, 4);
      part += __shfl_xor(part, 2);
      part += __shfl_xor(part, 1);
      if (g == 0) s_sc[n] = part;
    }
    __syncthreads();                                    // b4

    // P5+P6 fused (t<128): redundant in-wave softmax + u = P2S @ attn (4 accs)
    if (t < Hn) {
      int lane = t & 63;
      float v = (lane < Nn) ? s_sc[lane] : -INFINITY;
      float m = wredMaxAll(v);
      float e = (lane < Nn) ? __expf(v - m) : 0.f;
      float ssum = wredSumAll(e);
      float inv = frcp_(ssum);
      float a0 = 0.f, a1 = 0.f, a2 = 0.f, a3 = 0.f;
      #pragma unroll
      for (int n = 0; n < Nn; n += 4) {
        a0 += s_p2s[t][n]     * __shfl(e, n);
        a1 += s_p2s[t][n + 1] * __shfl(e, n + 1);
        a2 += s_p2s[t][n + 2] * __shfl(e, n + 2);
        a3 += s_p2s[t][n + 3] * __shfl(e, n + 3);
      }
      s_u[t] = ((a0 + a1) + (a2 + a3)) * inv;
    }
    __syncthreads();                                    // b5

    // P7: pointer scores — conflict-free h2 = i*32+g
    if (t < 32 * Nn) {
      int n = t >> 5, g = t & 31;
      float part = 0.f;
      #pragma unroll
      for (int i = 0; i < 4; ++i) {
        int h2 = i * 32 + g;
        part += s_pv[h2] * ftanh(s_ptr_pre[h2][n] + s_u[h2]);
      }
      part += __shfl_xor(part, 16);
      part += __shfl_xor(part, 8);
      part += __shfl_xor(part, 4);
      part += __shfl_xor(part, 2);
      part += __shfl_xor(part, 1);
      if (g == 0) s_p[n] = part;
    }
    __syncthreads();                                    // b6

    // P8: all-wave redundant argmax (ballot wave-uniform); dec in regs;
    //     no trailing barrier (s_p/s_gh rewrites fenced by b2..b5 of step k+1)
    {
      float v = (ln < Nn) ? (s_p[ln] + s_lm[ln]) : -INFINITY;
      float m = wredMaxAll(v);
      unsigned long long mask = __ballot(v == m);
      int amax = __ffsll(mask) - 1;
      dec0 = s_st[0][amax];
      dec1 = s_st[1][amax];
      if (t < 64) {
        float e = (ln < Nn) ? __expf(v - m) : 0.f;
        float ssum = wredSumAll(e);
        if (t == 0) {
          oi[step] = (float)amax;
          ol[step] = -__logf(ssum);
        }
      }
    }
  }
}

extern "C" void kernel_launch(void* const* d_in, const int* in_sizes, int n_in,
                              void* d_out, int out_size, void* d_ws, size_t ws_size,
                              hipStream_t stream) {
  (void)in_sizes; (void)n_in; (void)d_ws; (void)ws_size; (void)out_size;
  const float* adj    = (const float*)d_in[0];
  const float* stat   = (const float*)d_in[1];
  const float* dynp   = (const float*)d_in[2];
  const float* depot  = (const float*)d_in[3];
  const float* W_adj  = (const float*)d_in[4];
  const float* b_adj  = (const float*)d_in[5];
  const float* W_stat = (const float*)d_in[6];
  const float* b_stat = (const float*)d_in[7];
  const float* W_dyn  = (const float*)d_in[8];
  const float* b_dyn  = (const float*)d_in[9];
  const float* W_dec  = (const float*)d_in[10];
  const float* b_dec  = (const float*)d_in[11];
  const float* Wih    = (const float*)d_in[12];
  const float* Whh    = (const float*)d_in[13];
  const float* bih    = (const float*)d_in[14];
  const float* bhh    = (const float*)d_in[15];
  const float* attn_v = (const float*)d_in[16];
  const float* attn_W = (const float*)d_in[17];
  const float* ptr_v  = (const float*)d_in[18];
  const float* ptr_W  = (const float*)d_in[19];
  const float* x0     = (const float*)d_in[20];

  float* out = (float*)d_out;
  hipMemcpyAsync(out, dynp, (size_t)Bn * Sn * Nn * sizeof(float),
                 hipMemcpyDeviceToDevice, stream);
  float* out_idx  = out + Bn * Sn * Nn;
  float* out_logp = out + Bn * Sn * Nn + Bn * STEPS;

  cvrp_ptr_net_kernel<<<Bn, NTHREADS, 0, stream>>>(
      adj, stat, dynp, depot, W_adj, b_adj, W_stat, b_stat, W_dyn, b_dyn,
      W_dec, b_dec, Wih, Whh, bih, bhh, attn_v, attn_W, ptr_v, ptr_W, x0,
      out_idx, out_logp);
}

// Round 18
// 451.192 us; speedup vs baseline: 3.5875x; 1.0325x over previous
//
#include <hip/hip_runtime.h>
#include <math.h>

#define Bn 128
#define Nn 20
#define Hn 128
#define Sn 2
#define STEPS 100
#define NTHREADS 768

__device__ __forceinline__ float wredMaxAll(float v){
  #pragma unroll
  for (int o = 32; o; o >>= 1) v = fmaxf(v, __shfl_xor(v, o));
  return v;
}
__device__ __forceinline__ float wredSumAll(float v){
  #pragma unroll
  for (int o = 32; o; o >>= 1) v += __shfl_xor(v, o);
  return v;
}
__device__ __forceinline__ float frcp_(float x){ return __builtin_amdgcn_rcpf(x); }
__device__ __forceinline__ float ftanh(float x){
  float e = __expf(2.0f * x);
  return 1.0f - 2.0f * frcp_(e + 1.0f);
}
__device__ __forceinline__ float fsig(float x){ return frcp_(1.0f + __expf(-x)); }

// 768 threads, 5 barriers/step (r15 structure). New in r16:
//  - P4/P7 loop-invariants (attn_pre/ptr_pre/av/pv) hoisted to 16 regs/thread
//  - 4-accumulator qp chain in P3'
//  - P5 softmax without max-subtraction (|a[n]| <= ~10.2 bound, tanh<=1)
//  - logp output tail on wave 2 (waves 0-1 enter next P2 immediately)
__global__ __launch_bounds__(NTHREADS) void cvrp_ptr_net_kernel(
    const float* __restrict__ adj,   const float* __restrict__ stat,
    const float* __restrict__ dyn,   const float* __restrict__ depot,
    const float* __restrict__ W_adj, const float* __restrict__ b_adj,
    const float* __restrict__ W_stat,const float* __restrict__ b_stat,
    const float* __restrict__ W_dyn, const float* __restrict__ b_dyn,
    const float* __restrict__ W_dec, const float* __restrict__ b_dec,
    const float* __restrict__ Wih,   const float* __restrict__ Whh,
    const float* __restrict__ bih,   const float* __restrict__ bhh,
    const float* __restrict__ attn_v,const float* __restrict__ attn_W,
    const float* __restrict__ ptr_v, const float* __restrict__ ptr_W,
    const float* __restrict__ x0,
    float* __restrict__ out_idx, float* __restrict__ out_logp)
{
  __shared__ float s_attn_pre[Hn][Nn + 1];
  __shared__ float s_ptr_pre[Hn][Nn + 1];
  __shared__ float s_p2s[Hn][Nn + 1];
  __shared__ float s_eA[Hn][Nn + 1];
  __shared__ float s_eS[Hn][Nn + 1];
  __shared__ float s_eD[Hn][Nn + 1];
  __shared__ float s_adj[Nn][Nn];
  __shared__ float s_dep[Nn];
  __shared__ float s_st[Sn][Nn];
  __shared__ float s_dy[Sn][Nn];
  __shared__ float s_wdec0[Hn], s_wdec1[Hn], s_bdec[Hn];
  __shared__ float s_av[Hn], s_pv[Hn];
  __shared__ __align__(16) float s_h[Hn];
  __shared__ float s_gh[3 * Hn];       // Whh@h + bhh, written one step ahead
  __shared__ float s_q[Hn];
  __shared__ float s_sc[Nn];
  __shared__ float s_u[Hn];
  __shared__ float s_p[Nn];
  __shared__ float s_lm[Nn];

  const int b = blockIdx.x;
  const int t = threadIdx.x;
  const int wv = t >> 6;           // wave 0..11
  const int ln = t & 63;           // lane

  // gh pair-split: row = wv*32 + (ln&31), half = ln>>5
  const int rrow  = wv * 32 + (ln & 31);
  const int rhalf = ln >> 5;
  // q quad-split (t<512): qrow = wv*16 + (ln&15), quarter = ln>>4
  const int qrow   = wv * 16 + (ln & 15);
  const int qquart = ln >> 4;

  // ---- stage per-batch inputs & small weights ----
  for (int i = t; i < Nn * Nn; i += NTHREADS) s_adj[i / Nn][i % Nn] = adj[b * Nn * Nn + i];
  if (t < Nn) { float d = depot[b * Nn + t]; s_dep[t] = d; s_lm[t] = logf(d); }
  for (int i = t; i < Sn * Nn; i += NTHREADS) {
    s_st[i / Nn][i % Nn] = stat[b * Sn * Nn + i];
    s_dy[i / Nn][i % Nn] = dyn[b * Sn * Nn + i];
  }
  if (t < Hn) {
    s_wdec0[t] = W_dec[t * Sn]; s_wdec1[t] = W_dec[t * Sn + 1]; s_bdec[t] = b_dec[t];
    s_av[t] = attn_v[t]; s_pv[t] = ptr_v[t];
    s_h[t] = 0.0f;
  }
  if (t < 3 * Hn) s_gh[t] = bhh[t];   // gh(h0=0) = bhh
  __syncthreads();

  // ---- node embeddings ----
  for (int idx = t; idx < Hn * Nn; idx += NTHREADS) {
    int h = idx / Nn, n = idx - h * Nn;
    const float* wa = W_adj + h * (Nn + 1);
    float accA = b_adj[h];
    #pragma unroll
    for (int c = 0; c < Nn; ++c) accA += wa[c] * s_adj[c][n];
    accA += wa[Nn] * s_dep[n];
    s_eA[h][n] = accA;
    s_eS[h][n] = b_stat[h] + W_stat[h * Sn] * s_st[0][n] + W_stat[h * Sn + 1] * s_st[1][n];
    s_eD[h][n] = b_dyn[h]  + W_dyn[h * Sn]  * s_dy[0][n] + W_dyn[h * Sn + 1]  * s_dy[1][n];
  }
  __syncthreads();

  // ---- loop-invariant tables ----
  for (int idx = t; idx < Hn * Nn; idx += NTHREADS) {
    int h = idx / Nn, n = idx - h * Nn;
    const float* aw = attn_W + h * (4 * Hn);
    const float* pw = ptr_W + h * (2 * Hn);
    float acc = 0.f, p1 = 0.f, p2 = 0.f;
    for (int k = 0; k < Hn; ++k) {
      float es = s_eS[k][n];
      acc += aw[k] * s_eA[k][n] + aw[Hn + k] * es + aw[2 * Hn + k] * s_eD[k][n];
      p1  += pw[k] * es;
      p2  += pw[Hn + k] * es;
    }
    s_attn_pre[h][n] = acc; s_ptr_pre[h][n] = p1; s_p2s[h][n] = p2;
  }

  // ---- gi fold: t<128 holds 9 coeffs for its 3 gate-rows (named scalars) ----
  float c_r0 = 0.f, c_r1 = 0.f, c_rc = 0.f;
  float c_z0 = 0.f, c_z1 = 0.f, c_zc = 0.f;
  float c_n0 = 0.f, c_n1 = 0.f, c_nc = 0.f;
  if (t < Hn) {
    const float* wr_ = Wih + t * Hn;
    const float* wz_ = Wih + (Hn + t) * Hn;
    const float* wn_ = Wih + (2 * Hn + t) * Hn;
    for (int j = 0; j < Hn; ++j) {
      float d0 = s_wdec0[j], d1 = s_wdec1[j], db = s_bdec[j];
      float wr = wr_[j], wz = wz_[j], wn = wn_[j];
      c_r0 += wr * d0; c_r1 += wr * d1; c_rc += wr * db;
      c_z0 += wz * d0; c_z1 += wz * d1; c_zc += wz * db;
      c_n0 += wn * d0; c_n1 += wn * d1; c_nc += wn * db;
    }
    c_rc += bih[t]; c_zc += bih[Hn + t]; c_nc += bih[2 * Hn + t];
  }
  const float bhh_r = bhh[rrow];

  // ---- weight registers: Whh half-row (64) + Wa4 quarter-row (32) ----
  float wrowh[64];
  {
    const float4* src = (const float4*)(Whh + rrow * Hn + rhalf * 64);
    #pragma unroll
    for (int c = 0; c < 16; ++c) {
      float4 v = src[c];
      wrowh[4 * c] = v.x; wrowh[4 * c + 1] = v.y; wrowh[4 * c + 2] = v.z; wrowh[4 * c + 3] = v.w;
    }
  }
  float wa4q[32];
  if (t < 512) {
    const float4* src = (const float4*)(attn_W + qrow * 4 * Hn + 3 * Hn + qquart * 32);
    #pragma unroll
    for (int c = 0; c < 8; ++c) {
      float4 v = src[c];
      wa4q[4 * c] = v.x; wa4q[4 * c + 1] = v.y; wa4q[4 * c + 2] = v.z; wa4q[4 * c + 3] = v.w;
    }
  }
  __syncthreads();

  // ---- hoist P4/P7 loop-invariants to registers (16 floats, t<640) ----
  const int n_s = t >> 5, g_s = t & 31;
  float rap[4], rav[4], rpp[4], rpv[4];
  if (t < 32 * Nn) {
    #pragma unroll
    for (int i = 0; i < 4; ++i) {
      int h2 = i * 32 + g_s;
      rap[i] = s_attn_pre[h2][n_s];
      rpp[i] = s_ptr_pre[h2][n_s];
      rav[i] = s_av[h2];
      rpv[i] = s_pv[h2];
    }
  }

  float dec0 = x0[0], dec1 = x0[1];
  float* oi = out_idx + b * STEPS;
  float* ol = out_logp + b * STEPS;

  for (int step = 0; step < STEPS; ++step) {
    // P2: GRU with local gi (t<128): reads s_gh (written by P3' of prev step)
    if (t < Hn) {
      float gh_r = s_gh[t], gh_z = s_gh[Hn + t], gh_n = s_gh[2 * Hn + t];
      float gi_r = c_r0 * dec0 + c_r1 * dec1 + c_rc;
      float gi_z = c_z0 * dec0 + c_z1 * dec1 + c_zc;
      float gi_n = c_n0 * dec0 + c_n1 * dec1 + c_nc;
      float rr = fsig(gi_r + gh_r);
      float zz = fsig(gi_z + gh_z);
      float nn = ftanh(gi_n + rr * gh_n);
      s_h[t] = (1.0f - zz) * nn + zz * s_h[t];
    }
    __syncthreads();                                    // b2

    // P3': q = Wa4@h (quad-split, 4 accs) ; gh_next = Whh@h + bhh -> s_gh
    {
      if (t < 512) {
        float q0 = 0.f, q1 = 0.f, q2 = 0.f, q3 = 0.f;
        const float4* hh = (const float4*)(s_h + qquart * 32);
        #pragma unroll
        for (int c = 0; c < 8; ++c) {
          float4 hv = hh[c];
          q0 += wa4q[4 * c] * hv.x; q1 += wa4q[4 * c + 1] * hv.y;
          q2 += wa4q[4 * c + 2] * hv.z; q3 += wa4q[4 * c + 3] * hv.w;
        }
        float qp = (q0 + q1) + (q2 + q3);
        qp += __shfl_xor(qp, 16);
        qp += __shfl_xor(qp, 32);
        if (ln < 16) s_q[qrow] = qp;
      }
      float a0 = 0.f, a1 = 0.f, a2 = 0.f, a3 = 0.f;
      const float4* h4 = (const float4*)(s_h + rhalf * 64);
      #pragma unroll
      for (int c = 0; c < 16; ++c) {
        float4 hv = h4[c];
        a0 += wrowh[4 * c] * hv.x; a1 += wrowh[4 * c + 1] * hv.y;
        a2 += wrowh[4 * c + 2] * hv.z; a3 += wrowh[4 * c + 3] * hv.w;
      }
      float part = (a0 + a1) + (a2 + a3);
      part += __shfl_xor(part, 32);
      if ((ln >> 5) == 0) s_gh[rrow] = bhh_r + part;
    }
    __syncthreads();                                    // b3

    // P4: attention scores — invariants in regs; only s_q from LDS (broadcast)
    if (t < 32 * Nn) {
      float part = 0.f;
      #pragma unroll
      for (int i = 0; i < 4; ++i) {
        part += rav[i] * ftanh(rap[i] + s_q[i * 32 + g_s]);
      }
      part += __shfl_xor(part, 16);
      part += __shfl_xor(part, 8);
      part += __shfl_xor(part, 4);
      part += __shfl_xor(part, 2);
      part += __shfl_xor(part, 1);
      if (g_s == 0) s_sc[n_s] = part;
    }
    __syncthreads();                                    // b4

    // P5+P6 fused (t<128): softmax WITHOUT max-subtraction
    // (|a[n]| <= sum|av| ~ 10.2 since |tanh|<=1 -> exp can't overflow)
    if (t < Hn) {
      int lane = t & 63;
      float e = (lane < Nn) ? __expf(s_sc[lane]) : 0.f;
      float ssum = wredSumAll(e);
      float inv = frcp_(ssum);
      float a0 = 0.f, a1 = 0.f, a2 = 0.f, a3 = 0.f;
      #pragma unroll
      for (int n = 0; n < Nn; n += 4) {
        a0 += s_p2s[t][n]     * __shfl(e, n);
        a1 += s_p2s[t][n + 1] * __shfl(e, n + 1);
        a2 += s_p2s[t][n + 2] * __shfl(e, n + 2);
        a3 += s_p2s[t][n + 3] * __shfl(e, n + 3);
      }
      s_u[t] = ((a0 + a1) + (a2 + a3)) * inv;
    }
    __syncthreads();                                    // b5

    // P7: pointer scores — invariants in regs; only s_u from LDS (broadcast)
    if (t < 32 * Nn) {
      float part = 0.f;
      #pragma unroll
      for (int i = 0; i < 4; ++i) {
        part += rpv[i] * ftanh(rpp[i] + s_u[i * 32 + g_s]);
      }
      part += __shfl_xor(part, 16);
      part += __shfl_xor(part, 8);
      part += __shfl_xor(part, 4);
      part += __shfl_xor(part, 2);
      part += __shfl_xor(part, 1);
      if (g_s == 0) s_p[n_s] = part;
    }
    __syncthreads();                                    // b6

    // P8: all-wave redundant argmax -> dec in regs; logp tail on WAVE 2 so
    //     waves 0-1 enter P2(k+1) immediately; no trailing barrier.
    {
      float v = (ln < Nn) ? (s_p[ln] + s_lm[ln]) : -INFINITY;
      float m = wredMaxAll(v);
      unsigned long long mask = __ballot(v == m);
      int amax = __ffsll(mask) - 1;
      dec0 = s_st[0][amax];
      dec1 = s_st[1][amax];
      if (wv == 2) {
        float e = (ln < Nn) ? __expf(v - m) : 0.f;
        float ssum = wredSumAll(e);
        if (ln == 0) {
          oi[step] = (float)amax;
          ol[step] = -__logf(ssum);
        }
      }
    }
  }
}

extern "C" void kernel_launch(void* const* d_in, const int* in_sizes, int n_in,
                              void* d_out, int out_size, void* d_ws, size_t ws_size,
                              hipStream_t stream) {
  (void)in_sizes; (void)n_in; (void)d_ws; (void)ws_size; (void)out_size;
  const float* adj    = (const float*)d_in[0];
  const float* stat   = (const float*)d_in[1];
  const float* dynp   = (const float*)d_in[2];
  const float* depot  = (const float*)d_in[3];
  const float* W_adj  = (const float*)d_in[4];
  const float* b_adj  = (const float*)d_in[5];
  const float* W_stat = (const float*)d_in[6];
  const float* b_stat = (const float*)d_in[7];
  const float* W_dyn  = (const float*)d_in[8];
  const float* b_dyn  = (const float*)d_in[9];
  const float* W_dec  = (const float*)d_in[10];
  const float* b_dec  = (const float*)d_in[11];
  const float* Wih    = (const float*)d_in[12];
  const float* Whh    = (const float*)d_in[13];
  const float* bih    = (const float*)d_in[14];
  const float* bhh    = (const float*)d_in[15];
  const float* attn_v = (const float*)d_in[16];
  const float* attn_W = (const float*)d_in[17];
  const float* ptr_v  = (const float*)d_in[18];
  const float* ptr_W  = (const float*)d_in[19];
  const float* x0     = (const float*)d_in[20];

  float* out = (float*)d_out;
  hipMemcpyAsync(out, dynp, (size_t)Bn * Sn * Nn * sizeof(float),
                 hipMemcpyDeviceToDevice, stream);
  float* out_idx  = out + Bn * Sn * Nn;
  float* out_logp = out + Bn * Sn * Nn + Bn * STEPS;

  cvrp_ptr_net_kernel<<<Bn, NTHREADS, 0, stream>>>(
      adj, stat, dynp, depot, W_adj, b_adj, W_stat, b_stat, W_dyn, b_dyn,
      W_dec, b_dec, Wih, Whh, bih, bhh, attn_v, attn_W, ptr_v, ptr_W, x0,
      out_idx, out_logp);
}